// Round 2
// baseline (318.386 us; speedup 1.0000x reference)
//
#include <hip/hip_runtime.h>

#define EMBED 128   // node embedding dim
#define HID   64    // hidden dim

// ---------------------------------------------------------------------------
// FAST PATH — Kernel 1: per-node projection.
//   P[n][0:64]   = Z[n] @ W1[0:128]     (src half)
//   P[n][64:128] = Z[n] @ W1[128:256]   (dst half)
// Block = 256 = 4 waves. Wave w -> (node_sub = w>>1, half = w&1); lane j owns
// output column j. W1 column lives in 128 VGPRs (loaded coalesced once).
// Z reads go through a readfirstlane'd (wave-uniform) pointer -> scalar loads,
// inner loop is pure v_fmac_f32.
// ---------------------------------------------------------------------------
__global__ __launch_bounds__(256, 2)
void node_proj_kernel(const float* __restrict__ Z, const float* __restrict__ W1,
                      float* __restrict__ P, int n_nodes) {
    const int t    = threadIdx.x;
    const int j    = t & 63;          // output column (lane)
    const int half = (t >> 6) & 1;    // 0 = src proj, 1 = dst proj
    const int nsub = t >> 7;          // 0..1: which node of the pair

    const float* wcol = W1 + half * EMBED * HID + j;
    float w[EMBED];
#pragma unroll
    for (int k = 0; k < EMBED; ++k) w[k] = wcol[k * HID];

    const int stride = gridDim.x * 2;
    for (int base = blockIdx.x * 2; base < n_nodes; base += stride) {
        const int node = base + nsub;
        if (node < n_nodes) {
            const int un = __builtin_amdgcn_readfirstlane(node);
            const float* zp = Z + (size_t)un * EMBED;
            float a0 = 0.f, a1 = 0.f, a2 = 0.f, a3 = 0.f;
#pragma unroll
            for (int k = 0; k < EMBED; k += 4) {
                a0 = fmaf(zp[k + 0], w[k + 0], a0);
                a1 = fmaf(zp[k + 1], w[k + 1], a1);
                a2 = fmaf(zp[k + 2], w[k + 2], a2);
                a3 = fmaf(zp[k + 3], w[k + 3], a3);
            }
            P[(size_t)node * (2 * HID) + half * HID + j] = (a0 + a1) + (a2 + a3);
        }
    }
}

// ---------------------------------------------------------------------------
// FAST PATH — Kernel 2: per-edge MLP. 16 lanes/edge; lane l owns h[4l:4l+4].
//   h = relu(P[src][0:64] + P[dst][64:128] + b1);  out = h . W2 + b2
// float4 gathers (16B/lane, 16 lanes = one 256B P-row half, coalesced per
// edge-group). shfl_xor tree reduce over the 16 lanes.
// ---------------------------------------------------------------------------
__global__ __launch_bounds__(256)
void edge_mlp_kernel(const float* __restrict__ P, const int* __restrict__ src,
                     const int* __restrict__ dst, const float* __restrict__ b1,
                     const float* __restrict__ W2, const float* __restrict__ b2,
                     float* __restrict__ out, int n_edges) {
    const int gtid   = blockIdx.x * 256 + threadIdx.x;
    const int lane16 = gtid & 15;
    const int e      = gtid >> 4;
    if (e >= n_edges) return;

    const float4 w2v = *(const float4*)(W2 + lane16 * 4);
    const float4 b1v = *(const float4*)(b1 + lane16 * 4);

    const int s = src[e];
    const int d = dst[e];
    const float4 ps = *(const float4*)(P + (size_t)s * 128 + lane16 * 4);
    const float4 pd = *(const float4*)(P + (size_t)d * 128 + 64 + lane16 * 4);

    const float h0 = fmaxf(ps.x + pd.x + b1v.x, 0.f);
    const float h1 = fmaxf(ps.y + pd.y + b1v.y, 0.f);
    const float h2 = fmaxf(ps.z + pd.z + b1v.z, 0.f);
    const float h3 = fmaxf(ps.w + pd.w + b1v.w, 0.f);

    float part = h0 * w2v.x + h1 * w2v.y + h2 * w2v.z + h3 * w2v.w;
    part += __shfl_xor(part, 8, 16);
    part += __shfl_xor(part, 4, 16);
    part += __shfl_xor(part, 2, 16);
    part += __shfl_xor(part, 1, 16);

    if (lane16 == 0) out[e] = part + b2[0];
}

// ---------------------------------------------------------------------------
// FALLBACK (only if ws_size < P bytes): workspace-free direct per-edge MLP.
// W1 (64 KB) staged in LDS. 16 lanes/edge, lane l16 computes h[4*l16 .. +3]
// directly from Z[src], Z[dst]. Correctness path — not perf-tuned.
// ---------------------------------------------------------------------------
__global__ __launch_bounds__(256)
void edge_direct_kernel(const float* __restrict__ Z, const int* __restrict__ src,
                        const int* __restrict__ dst, const float* __restrict__ W1,
                        const float* __restrict__ b1, const float* __restrict__ W2,
                        const float* __restrict__ b2, float* __restrict__ out,
                        int n_edges) {
    __shared__ float w1s[2 * EMBED * HID];   // 64 KB
    for (int i = threadIdx.x; i < 2 * EMBED * HID; i += 256) w1s[i] = W1[i];
    __syncthreads();

    const int gtid   = blockIdx.x * 256 + threadIdx.x;
    const int lane16 = gtid & 15;
    const int e      = gtid >> 4;
    if (e >= n_edges) return;

    const int s = src[e];
    const int d = dst[e];
    const float* zs = Z + (size_t)s * EMBED;
    const float* zd = Z + (size_t)d * EMBED;

    float h[4] = {b1[lane16 * 4 + 0], b1[lane16 * 4 + 1],
                  b1[lane16 * 4 + 2], b1[lane16 * 4 + 3]};
    for (int k = 0; k < EMBED; ++k) {
        const float zsk = zs[k];
        const float zdk = zd[k];
        const float4 w1a = *(const float4*)(&w1s[k * HID + lane16 * 4]);
        const float4 w1b = *(const float4*)(&w1s[(EMBED + k) * HID + lane16 * 4]);
        h[0] = fmaf(zsk, w1a.x, fmaf(zdk, w1b.x, h[0]));
        h[1] = fmaf(zsk, w1a.y, fmaf(zdk, w1b.y, h[1]));
        h[2] = fmaf(zsk, w1a.z, fmaf(zdk, w1b.z, h[2]));
        h[3] = fmaf(zsk, w1a.w, fmaf(zdk, w1b.w, h[3]));
    }

    const float4 w2v = *(const float4*)(W2 + lane16 * 4);
    float part = fmaxf(h[0], 0.f) * w2v.x + fmaxf(h[1], 0.f) * w2v.y +
                 fmaxf(h[2], 0.f) * w2v.z + fmaxf(h[3], 0.f) * w2v.w;
    part += __shfl_xor(part, 8, 16);
    part += __shfl_xor(part, 4, 16);
    part += __shfl_xor(part, 2, 16);
    part += __shfl_xor(part, 1, 16);

    if (lane16 == 0) out[e] = part + b2[0];
}

extern "C" void kernel_launch(void* const* d_in, const int* in_sizes, int n_in,
                              void* d_out, int out_size, void* d_ws, size_t ws_size,
                              hipStream_t stream) {
    const float* Z  = (const float*)d_in[0];
    const int*   EI = (const int*)d_in[1];   // [2, E] stacked: src then dst
    const float* W1 = (const float*)d_in[2]; // [256, 64] row-major
    const float* b1 = (const float*)d_in[3]; // [64]
    const float* W2 = (const float*)d_in[4]; // [64, 1] -> flat [64]
    const float* b2 = (const float*)d_in[5]; // [1]
    float* out = (float*)d_out;

    const int n_nodes = in_sizes[0] / EMBED;
    const int E       = in_sizes[1] / 2;

    const size_t p_bytes = (size_t)n_nodes * (2 * HID) * sizeof(float);
    const int edge_threads = E * 16;
    const int edge_blocks  = (edge_threads + 255) / 256;

    if (ws_size >= p_bytes) {
        float* P = (float*)d_ws;             // [n_nodes][128] fp32 = 51.2 MB
        node_proj_kernel<<<1024, 256, 0, stream>>>(Z, W1, P, n_nodes);
        edge_mlp_kernel<<<edge_blocks, 256, 0, stream>>>(
            P, EI, EI + E, b1, W2, b2, out, E);
    } else {
        edge_direct_kernel<<<edge_blocks, 256, 0, stream>>>(
            Z, EI, EI + E, W1, b1, W2, b2, out, E);
    }
}

// Round 4
// 210.743 us; speedup vs baseline: 1.5108x; 1.5108x over previous
//
#include <hip/hip_runtime.h>

#define EMBED 128   // node embedding dim
#define HID   64    // hidden dim

// ---------------------------------------------------------------------------
// Kernel 1: node projection P = Z @ B2, B2[k][jj] = jj<64 ? W1[k][jj]
//                                                 : W1[128+k][jj-64]
// P[n][0:64] = src-half + b1/2, P[n][64:128] = dst-half + b1/2.
// Explicit register-tiled GEMM: B2 in LDS (64 KB), thread tile = 8 nodes x
// 8 outputs (64 regs, all compile-time indexed), z via float4 global loads.
// Block 256 thr: tj = t&15 -> output group j0=8*tj (covers 128), tn = t>>4
// -> 8 nodes each -> 128 nodes/block-iter. 2 blocks/CU (LDS-limited).
// ---------------------------------------------------------------------------
__global__ __launch_bounds__(256, 2)
void node_proj_kernel(const float* __restrict__ Z, const float* __restrict__ W1,
                      const float* __restrict__ b1, float* __restrict__ P,
                      int n_nodes) {
    __shared__ float w1s[EMBED * 128];   // B2, 64 KB
    for (int idx = threadIdx.x; idx < EMBED * 128; idx += 256) {
        const int k = idx >> 7, jj = idx & 127;
        w1s[idx] = (jj < HID) ? W1[k * HID + jj]
                              : W1[(EMBED + k) * HID + (jj - HID)];
    }

    const int tj = threadIdx.x & 15;
    const int tn = threadIdx.x >> 4;
    const int j0 = tj * 8;

    float bh[8];
#pragma unroll
    for (int c = 0; c < 8; ++c) bh[c] = 0.5f * b1[(j0 + c) & (HID - 1)];

    __syncthreads();

    for (int base = blockIdx.x * 128; base < n_nodes; base += gridDim.x * 128) {
        const int node0 = base + tn * 8;

        int off[8];
#pragma unroll
        for (int i = 0; i < 8; ++i) {
            const int n = node0 + i;
            off[i] = (n < n_nodes ? n : n_nodes - 1) * EMBED;  // clamp loads
        }

        float acc[8][8];
#pragma unroll
        for (int i = 0; i < 8; ++i)
#pragma unroll
            for (int c = 0; c < 8; ++c) acc[i][c] = 0.f;

#pragma unroll 2
        for (int k0 = 0; k0 < EMBED; k0 += 4) {
            float4 zv[8];
#pragma unroll
            for (int i = 0; i < 8; ++i)
                zv[i] = *(const float4*)(Z + off[i] + k0);

            float4 wv[4][2];
#pragma unroll
            for (int kk = 0; kk < 4; ++kk) {
                wv[kk][0] = *(const float4*)(&w1s[(k0 + kk) * 128 + j0]);
                wv[kk][1] = *(const float4*)(&w1s[(k0 + kk) * 128 + j0 + 4]);
            }

#pragma unroll
            for (int i = 0; i < 8; ++i) {
                const float zk0 = zv[i].x, zk1 = zv[i].y, zk2 = zv[i].z, zk3 = zv[i].w;
#pragma unroll
                for (int kk = 0; kk < 4; ++kk) {
                    const float z = (kk == 0) ? zk0 : (kk == 1) ? zk1 : (kk == 2) ? zk2 : zk3;
                    acc[i][0] = fmaf(z, wv[kk][0].x, acc[i][0]);
                    acc[i][1] = fmaf(z, wv[kk][0].y, acc[i][1]);
                    acc[i][2] = fmaf(z, wv[kk][0].z, acc[i][2]);
                    acc[i][3] = fmaf(z, wv[kk][0].w, acc[i][3]);
                    acc[i][4] = fmaf(z, wv[kk][1].x, acc[i][4]);
                    acc[i][5] = fmaf(z, wv[kk][1].y, acc[i][5]);
                    acc[i][6] = fmaf(z, wv[kk][1].z, acc[i][6]);
                    acc[i][7] = fmaf(z, wv[kk][1].w, acc[i][7]);
                }
            }
        }

#pragma unroll
        for (int i = 0; i < 8; ++i) {
            const int n = node0 + i;
            if (n < n_nodes) {
                const float4 lo = {acc[i][0] + bh[0], acc[i][1] + bh[1],
                                   acc[i][2] + bh[2], acc[i][3] + bh[3]};
                const float4 hi = {acc[i][4] + bh[4], acc[i][5] + bh[5],
                                   acc[i][6] + bh[6], acc[i][7] + bh[7]};
                *(float4*)(P + (size_t)n * 128 + j0)     = lo;
                *(float4*)(P + (size_t)n * 128 + j0 + 4) = hi;
            }
        }
    }
}

// ---------------------------------------------------------------------------
// Kernel 2: per-edge MLP, b1 pre-folded into P. 16 lanes/edge, 2 edges per
// thread (4 independent 256B gathers in flight). shfl_xor tree over 16 lanes.
//   out[e] = b2 + sum_j relu(P[s][j] + P[d][64+j]) * W2[j]
// ---------------------------------------------------------------------------
__global__ __launch_bounds__(256)
void edge_mlp_kernel(const float* __restrict__ P, const int* __restrict__ src,
                     const int* __restrict__ dst, const float* __restrict__ W2,
                     const float* __restrict__ b2, float* __restrict__ out,
                     int n_edges) {
    const int gtid   = blockIdx.x * 256 + threadIdx.x;
    const int lane16 = gtid & 15;
    const int e1     = gtid >> 4;
    const int half   = (n_edges + 1) >> 1;
    if (e1 >= half) return;
    const int e2 = e1 + half;
    const bool has2 = e2 < n_edges;

    const float4 w2v = *(const float4*)(W2 + lane16 * 4);

    const int s1 = src[e1], d1 = dst[e1];
    const int s2 = has2 ? src[e2] : s1;
    const int d2 = has2 ? dst[e2] : d1;

    const float4 ps1 = *(const float4*)(P + (size_t)s1 * 128 + lane16 * 4);
    const float4 pd1 = *(const float4*)(P + (size_t)d1 * 128 + 64 + lane16 * 4);
    const float4 ps2 = *(const float4*)(P + (size_t)s2 * 128 + lane16 * 4);
    const float4 pd2 = *(const float4*)(P + (size_t)d2 * 128 + 64 + lane16 * 4);

    float p1 = fmaxf(ps1.x + pd1.x, 0.f) * w2v.x + fmaxf(ps1.y + pd1.y, 0.f) * w2v.y
             + fmaxf(ps1.z + pd1.z, 0.f) * w2v.z + fmaxf(ps1.w + pd1.w, 0.f) * w2v.w;
    float p2 = fmaxf(ps2.x + pd2.x, 0.f) * w2v.x + fmaxf(ps2.y + pd2.y, 0.f) * w2v.y
             + fmaxf(ps2.z + pd2.z, 0.f) * w2v.z + fmaxf(ps2.w + pd2.w, 0.f) * w2v.w;

    p1 += __shfl_xor(p1, 8, 16);  p2 += __shfl_xor(p2, 8, 16);
    p1 += __shfl_xor(p1, 4, 16);  p2 += __shfl_xor(p2, 4, 16);
    p1 += __shfl_xor(p1, 2, 16);  p2 += __shfl_xor(p2, 2, 16);
    p1 += __shfl_xor(p1, 1, 16);  p2 += __shfl_xor(p2, 1, 16);

    if (lane16 == 0) {
        const float bb = b2[0];
        out[e1] = p1 + bb;
        if (has2) out[e2] = p2 + bb;
    }
}

// ---------------------------------------------------------------------------
// FALLBACK (ws too small): workspace-free direct per-edge MLP, W1 in LDS.
// ---------------------------------------------------------------------------
__global__ __launch_bounds__(256)
void edge_direct_kernel(const float* __restrict__ Z, const int* __restrict__ src,
                        const int* __restrict__ dst, const float* __restrict__ W1,
                        const float* __restrict__ b1, const float* __restrict__ W2,
                        const float* __restrict__ b2, float* __restrict__ out,
                        int n_edges) {
    __shared__ float w1s[2 * EMBED * HID];   // 64 KB
    for (int i = threadIdx.x; i < 2 * EMBED * HID; i += 256) w1s[i] = W1[i];
    __syncthreads();

    const int gtid   = blockIdx.x * 256 + threadIdx.x;
    const int lane16 = gtid & 15;
    const int e      = gtid >> 4;
    if (e >= n_edges) return;

    const int s = src[e];
    const int d = dst[e];
    const float* zs = Z + (size_t)s * EMBED;
    const float* zd = Z + (size_t)d * EMBED;

    float h[4] = {b1[lane16 * 4 + 0], b1[lane16 * 4 + 1],
                  b1[lane16 * 4 + 2], b1[lane16 * 4 + 3]};
    for (int k = 0; k < EMBED; ++k) {
        const float zsk = zs[k];
        const float zdk = zd[k];
        const float4 w1a = *(const float4*)(&w1s[k * HID + lane16 * 4]);
        const float4 w1b = *(const float4*)(&w1s[(EMBED + k) * HID + lane16 * 4]);
        h[0] = fmaf(zsk, w1a.x, fmaf(zdk, w1b.x, h[0]));
        h[1] = fmaf(zsk, w1a.y, fmaf(zdk, w1b.y, h[1]));
        h[2] = fmaf(zsk, w1a.z, fmaf(zdk, w1b.z, h[2]));
        h[3] = fmaf(zsk, w1a.w, fmaf(zdk, w1b.w, h[3]));
    }

    const float4 w2v = *(const float4*)(W2 + lane16 * 4);
    float part = fmaxf(h[0], 0.f) * w2v.x + fmaxf(h[1], 0.f) * w2v.y +
                 fmaxf(h[2], 0.f) * w2v.z + fmaxf(h[3], 0.f) * w2v.w;
    part += __shfl_xor(part, 8, 16);
    part += __shfl_xor(part, 4, 16);
    part += __shfl_xor(part, 2, 16);
    part += __shfl_xor(part, 1, 16);

    if (lane16 == 0) out[e] = part + b2[0];
}

extern "C" void kernel_launch(void* const* d_in, const int* in_sizes, int n_in,
                              void* d_out, int out_size, void* d_ws, size_t ws_size,
                              hipStream_t stream) {
    const float* Z  = (const float*)d_in[0];
    const int*   EI = (const int*)d_in[1];   // [2, E]: src row then dst row
    const float* W1 = (const float*)d_in[2]; // [256, 64] row-major
    const float* b1 = (const float*)d_in[3]; // [64]
    const float* W2 = (const float*)d_in[4]; // [64]
    const float* b2 = (const float*)d_in[5]; // [1]
    float* out = (float*)d_out;

    const int n_nodes = in_sizes[0] / EMBED;
    const int E       = in_sizes[1] / 2;

    const size_t p_bytes = (size_t)n_nodes * (2 * HID) * sizeof(float);

    if (ws_size >= p_bytes) {
        float* P = (float*)d_ws;             // [n_nodes][128] fp32
        const int node_blocks = (n_nodes + 127) / 128;
        node_proj_kernel<<<node_blocks, 256, 0, stream>>>(Z, W1, b1, P, n_nodes);

        const int half = (E + 1) >> 1;
        const int edge_blocks = (half * 16 + 255) / 256;
        edge_mlp_kernel<<<edge_blocks, 256, 0, stream>>>(
            P, EI, EI + E, W2, b2, out, E);
    } else {
        const int edge_blocks = (E * 16 + 255) / 256;
        edge_direct_kernel<<<edge_blocks, 256, 0, stream>>>(
            Z, EI, EI + E, W1, b1, W2, b2, out, E);
    }
}